// Round 8
// baseline (83.112 us; speedup 1.0000x reference)
//
#include <hip/hip_runtime.h>
#include <hip/hip_bf16.h>

typedef __attribute__((ext_vector_type(8))) short bf16x8;
typedef __attribute__((ext_vector_type(4))) float f32x4;

// exp(v/T - 5) with T=0.2  ==  exp2( (v-1) * 5*log2(e) )
#define EXP_SCALE 7.213475204444817f

__device__ __forceinline__ float fast_exp2(float x) {
#if __has_builtin(__builtin_amdgcn_exp2f)
  return __builtin_amdgcn_exp2f(x);
#else
  return exp2f(x);
#endif
}

__device__ __forceinline__ unsigned short f32_to_bf16(float f) {
  unsigned int u = __float_as_uint(f);
  unsigned int r = (u + 0x7FFFu + ((u >> 16) & 1u)) >> 16;
  return (unsigned short)r;
}

// z is stored SWIZZLED in MFMA-fragment order:
//   shorts addr = tile*2048 + kk*512 + slot*8 + rem
// where tile = row>>4, c = row&15, element e: kk = e>>5, q = (e>>3)&3,
// rem = e&7, slot = q*16 + c. A wave (lane = q*16+c) loads one (tile,kk)
// fragment as one contiguous 1KB load.

// Kernel 1: L2-normalize rows -> swizzled bf16 z. Zeroes out[0] only
// (partial-sum buffers need no init: k_finish reads only written entries).
__global__ __launch_bounds__(256) void k_normalize(
    const float* __restrict__ emb_i, const float* __restrict__ emb_j,
    unsigned short* __restrict__ z, float* __restrict__ out)
{
  if (blockIdx.x == 0 && threadIdx.x == 0) out[0] = 0.0f;
  const int w = threadIdx.x >> 6;
  const int lane = threadIdx.x & 63;
  const int row = (blockIdx.x << 2) + w;
  const float* src = (row < 4096) ? (emb_i + row * 128) : (emb_j + (row - 4096) * 128);
  float2 v = reinterpret_cast<const float2*>(src)[lane];
  float ss = v.x * v.x + v.y * v.y;
  #pragma unroll
  for (int m = 1; m < 64; m <<= 1) ss += __shfl_xor(ss, m, 64);
  float rinv = 1.0f / sqrtf(ss);
  ushort2 st;
  st.x = f32_to_bf16(v.x * rinv);
  st.y = f32_to_bf16(v.y * rinv);
  const int e = lane << 1;
  const int kk = e >> 5;
  const int q = (e >> 3) & 3;
  const int rem = e & 7;
  const int tile = row >> 4;
  const int c = row & 15;
  unsigned short* dst = z + tile * 2048 + kk * 512 + ((q << 4) + c) * 8 + rem;
  *reinterpret_cast<ushort2*>(dst) = st;
}

// Kernel 2 (symmetric, NO atomics): cell = 64 rows x 512 cols, launched iff
// rb < 8(ch+1), ch 0..15 -> 1088 cells (53% of full work).
// Row-path partials -> rpart[ch][8192] (plain store, disjoint).
// Strictly-upper cells (rb < 8ch) also compute per-column sums over their
// 64 rows -> cpart[rb][8192] (plain store, disjoint; only valid entries
// are read back). k_finish does the two-level sum.
// Diagonal exp term (==1 for unit rows) kept; k_finish subtracts 1.
__global__ __launch_bounds__(256, 3) void k_simlse(
    const unsigned short* __restrict__ z,
    float* __restrict__ rpart,    // [16][8192]
    float* __restrict__ cpart,    // [128][8192]
    float* __restrict__ rowpos)   // [4096] (row r>=4096 mirrors r-4096)
{
  const int w = threadIdx.x >> 6;
  const int lane = threadIdx.x & 63;
  const int q = lane >> 4;
  const int c = lane & 15;

  // cell id -> (ch, rb): start(ch) = 4ch(ch+1), cells(ch) = 8(ch+1)
  int ch = 0;
  while ((int)blockIdx.x >= 4 * (ch + 1) * (ch + 2)) ++ch;
  const int rb = blockIdx.x - 4 * ch * (ch + 1);   // 0 .. 8ch+7
  const int R0 = rb << 6;                          // 64-row block
  const bool upper = (rb < (ch << 3));             // strictly above diagonal band

  // ---- stage A (tiles R0/16 .. +3, 16KB) into LDS, then registers ----
  __shared__ short smem[8192];          // 16KB
  {
    const unsigned short* zA = z + (R0 >> 4) * 2048;
    #pragma unroll
    for (int j = 0; j < 4; ++j) {
      const int v = (j << 8) + threadIdx.x;        // 0..1023 vec8 chunks
      *reinterpret_cast<bf16x8*>(&smem[v << 3]) =
          *reinterpret_cast<const bf16x8*>(zA + (v << 3));
    }
  }
  __syncthreads();
  bf16x8 a[4][4];
  #pragma unroll
  for (int rg = 0; rg < 4; ++rg)
    #pragma unroll
    for (int kk = 0; kk < 4; ++kk)
      a[rg][kk] = *reinterpret_cast<const bf16x8*>(
          &smem[rg * 2048 + kk * 512 + (lane << 3)]);

  float acc[4][4];
  #pragma unroll
  for (int rg = 0; rg < 4; ++rg)
    #pragma unroll
    for (int e = 0; e < 4; ++e) acc[rg][e] = 0.0f;
  float pacc[4] = {0.f, 0.f, 0.f, 0.f};

  __shared__ float lsum[4][64];
  __shared__ float lpos[4][16];

  // wave w walks 16-col tiles ct = 32ch + w + 4i, i = 0..7
  const int ct0 = (ch << 5) + w;
  const unsigned short* bwave = z + ct0 * 2048 + (lane << 3);

  // positive tile: owned by this cell iff its 32-tile chunk matches.
  const int pos0t = ((R0 + 4096) & 8191) >> 4;
  const int ipb = ((pos0t >> 5) == ch) ? ((pos0t & 31) >> 2) : -99;

  bf16x8 b0[4], b1[4];
  auto ldb = [&](bf16x8 (&dst)[4], int idx) {
    const unsigned short* p = bwave + idx * 8192;   // stride 4 tiles
    dst[0] = *reinterpret_cast<const bf16x8*>(p);
    dst[1] = *reinterpret_cast<const bf16x8*>(p + 512);
    dst[2] = *reinterpret_cast<const bf16x8*>(p + 1024);
    dst[3] = *reinterpret_cast<const bf16x8*>(p + 1536);
  };

  auto process = [&](const bf16x8 (&bb)[4], int i) {
    f32x4 cc[4];
    #pragma unroll
    for (int rr = 0; rr < 4; ++rr) cc[rr] = f32x4{0.f, 0.f, 0.f, 0.f};
    #pragma unroll
    for (int kk = 0; kk < 4; ++kk)
      #pragma unroll
      for (int rr = 0; rr < 4; ++rr)
        cc[rr] = __builtin_amdgcn_mfma_f32_16x16x32_bf16(
            a[rr][kk], bb[kk], cc[rr], 0, 0, 0);
    float colp0 = 0.0f, colp1 = 0.0f;   // two chains to cut dep latency
    #pragma unroll
    for (int rr = 0; rr < 4; ++rr)
      #pragma unroll
      for (int e = 0; e < 4; ++e) {
        float t = fast_exp2(__builtin_fmaf(cc[rr][e], EXP_SCALE, -EXP_SCALE));
        acc[rr][e] += t;
        if (upper) { if (rr & 1) colp1 += t; else colp0 += t; }
      }
    if (upper) {                         // column sums over the 64 rows
      float colp = colp0 + colp1;
      colp += __shfl_xor(colp, 16, 64);
      colp += __shfl_xor(colp, 32, 64);
      if (lane < 16)                     // direct store: this wave owns tile ct
        cpart[(rb << 13) + (((ct0 + (i << 2)) << 4) + c)] = colp;
    }
    if (i == ipb) {                      // rare, wave-uniform
      #pragma unroll
      for (int rr = 0; rr < 4; ++rr) {
        if (rr == w) {
          #pragma unroll
          for (int e = 0; e < 4; ++e)
            if (c == ((q << 2) + e)) pacc[e] = cc[rr][e] * 5.0f;
        }
      }
    }
  };

  ldb(b0, 0);
  #pragma unroll 1
  for (int i = 0; i < 8; i += 2) {
    ldb(b1, i + 1);
    process(b0, i);
    if (i + 2 < 8) ldb(b0, i + 2);
    process(b1, i + 1);
  }

  // Reduce row-sums over the 16 cols per tile (c-group: xor 1,2,4,8)
  #pragma unroll
  for (int m = 1; m < 16; m <<= 1) {
    #pragma unroll
    for (int rg = 0; rg < 4; ++rg)
      #pragma unroll
      for (int e = 0; e < 4; ++e)
        acc[rg][e] += __shfl_xor(acc[rg][e], m, 64);
    #pragma unroll
    for (int e = 0; e < 4; ++e) pacc[e] += __shfl_xor(pacc[e], m, 64);
  }

  if (c == 0) {
    #pragma unroll
    for (int rg = 0; rg < 4; ++rg)
      #pragma unroll
      for (int e = 0; e < 4; ++e)
        lsum[w][rg * 16 + (q << 2) + e] = acc[rg][e];
    #pragma unroll
    for (int e = 0; e < 4; ++e) lpos[w][(q << 2) + e] = pacc[e];
  }
  __syncthreads();

  if (threadIdx.x < 64) {
    const int t = threadIdx.x;
    float s = lsum[0][t] + lsum[1][t] + lsum[2][t] + lsum[3][t];
    rpart[(ch << 13) + R0 + t] = s;      // plain store, disjoint per cell
    if (ipb != -99)                      // this cell owns the positive cols
      rowpos[R0 + t] = lpos[t >> 4][t & 15];
  }
}

// Kernel 3: tot = sum of row-path partials (ch >= r>>9) + col-path partials
// (rb < 8*(r>>9)) - 1 (diagonal); lse = 5 + log(tot); loss = mean(lse - pos).
// pos for r>=4096 mirrors r-4096 (S symmetric).
__global__ __launch_bounds__(256) void k_finish(
    const float* __restrict__ rpart, const float* __restrict__ cpart,
    const float* __restrict__ rowpos, float* __restrict__ out)
{
  const int r = blockIdx.x * 256 + threadIdx.x;
  const int chr = r >> 9;                // uniform per block (256 | 512 aligned)
  float t0 = -1.0f, t1 = 0.0f;
  for (int ch = chr; ch < 16; ++ch) t0 += rpart[(ch << 13) + r];
  const int nrb = chr << 3;
  #pragma unroll 4
  for (int rb = 0; rb < nrb; rb += 2) {  // nrb is even
    t0 += cpart[(rb << 13) + r];
    t1 += cpart[((rb + 1) << 13) + r];
  }
  float tot = t0 + t1;
  float v = 5.0f + logf(tot) - rowpos[r & 4095];
  #pragma unroll
  for (int m = 1; m < 64; m <<= 1) v += __shfl_xor(v, m, 64);
  __shared__ float red[4];
  if ((threadIdx.x & 63) == 0) red[threadIdx.x >> 6] = v;
  __syncthreads();
  if (threadIdx.x == 0)
    atomicAdd(out, (red[0] + red[1] + red[2] + red[3]) * (1.0f / 8192.0f));
}

extern "C" void kernel_launch(void* const* d_in, const int* in_sizes, int n_in,
                              void* d_out, int out_size, void* d_ws, size_t ws_size,
                              hipStream_t stream) {
  const float* emb_i = (const float*)d_in[0];
  const float* emb_j = (const float*)d_in[1];
  unsigned short* z = (unsigned short*)d_ws;                       // 2 MB (swizzled)
  float* rpart = (float*)((char*)d_ws + (2 << 20));                // [16][8192] = 512 KB
  float* cpart = rpart + 16 * 8192;                                // [128][8192] = 4 MB
  float* rowpos = cpart + 128 * 8192;                              // [4096] = 16 KB
  float* out = (float*)d_out;

  k_normalize<<<2048, 256, 0, stream>>>(emb_i, emb_j, z, out);
  k_simlse<<<1088, 256, 0, stream>>>(z, rpart, cpart, rowpos);
  k_finish<<<32, 256, 0, stream>>>(rpart, cpart, rowpos, out);
}

// Round 9
// 82.907 us; speedup vs baseline: 1.0025x; 1.0025x over previous
//
#include <hip/hip_runtime.h>
#include <hip/hip_bf16.h>

typedef __attribute__((ext_vector_type(8))) short bf16x8;
typedef __attribute__((ext_vector_type(4))) float f32x4;

// exp(v/T - 5) with T=0.2  ==  exp2( (v-1) * 5*log2(e) )
#define EXP_SCALE 7.213475204444817f

__device__ __forceinline__ float fast_exp2(float x) {
#if __has_builtin(__builtin_amdgcn_exp2f)
  return __builtin_amdgcn_exp2f(x);
#else
  return exp2f(x);
#endif
}

__device__ __forceinline__ unsigned short f32_to_bf16(float f) {
  unsigned int u = __float_as_uint(f);
  unsigned int r = (u + 0x7FFFu + ((u >> 16) & 1u)) >> 16;
  return (unsigned short)r;
}

// z is stored SWIZZLED in MFMA-fragment order:
//   shorts addr = tile*2048 + kk*512 + slot*8 + rem
// where tile = row>>4, c = row&15, element e: kk = e>>5, q = (e>>3)&3,
// rem = e&7, slot = q*16 + c. A wave (lane = q*16+c) loads one (tile,kk)
// fragment as one contiguous 1KB load.

// Kernel 1: L2-normalize rows -> swizzled bf16 z. Block = one 16-row tile.
// Thread t: row c = t>>4, element-block sub = t&15 (8 floats). Reads are
// fully coalesced (wave = 4 rows x 512B contiguous); the block writes its
// entire 8KB tile with 256 distinct 16B stores (full-line coverage).
__global__ __launch_bounds__(256) void k_normalize(
    const float* __restrict__ emb_i, const float* __restrict__ emb_j,
    unsigned short* __restrict__ z, float* __restrict__ out)
{
  if (blockIdx.x == 0 && threadIdx.x == 0) out[0] = 0.0f;
  const int t = threadIdx.x;
  const int c = t >> 4;               // row within tile (0..15)
  const int sub = t & 15;             // 8-element block within row
  const int row = (blockIdx.x << 4) + c;
  const float* src = (row < 4096) ? (emb_i + row * 128) : (emb_j + (row - 4096) * 128);
  float4 v0 = reinterpret_cast<const float4*>(src)[sub * 2];
  float4 v1 = reinterpret_cast<const float4*>(src)[sub * 2 + 1];
  float ss = v0.x*v0.x + v0.y*v0.y + v0.z*v0.z + v0.w*v0.w
           + v1.x*v1.x + v1.y*v1.y + v1.z*v1.z + v1.w*v1.w;
  // reduce across the 16 threads of this row (lanes share l>>4 group)
  #pragma unroll
  for (int m = 1; m < 16; m <<= 1) ss += __shfl_xor(ss, m, 64);
  float rinv = 1.0f / sqrtf(ss);
  unsigned short st[8];
  st[0] = f32_to_bf16(v0.x * rinv); st[1] = f32_to_bf16(v0.y * rinv);
  st[2] = f32_to_bf16(v0.z * rinv); st[3] = f32_to_bf16(v0.w * rinv);
  st[4] = f32_to_bf16(v1.x * rinv); st[5] = f32_to_bf16(v1.y * rinv);
  st[6] = f32_to_bf16(v1.z * rinv); st[7] = f32_to_bf16(v1.w * rinv);
  // swizzled dst: kk = sub>>2, q = sub&3, slot = q*16 + c
  unsigned short* dst = z + blockIdx.x * 2048 + (sub >> 2) * 512 +
                        (((sub & 3) << 4) + c) * 8;
  *reinterpret_cast<bf16x8*>(dst) = *reinterpret_cast<bf16x8*>(st);
}

// Kernel 2 (symmetric, no atomics, no LDS staging): cell = 64 rows x 512
// cols, launched iff rb < 8(ch+1), ch 0..15 -> 1088 cells (53% of work).
// A fragments loaded DIRECTLY from global (swizzled layout = contiguous
// 1KB wave loads). Row partials -> rpart[ch][8192]; strictly-upper cells
// also store per-column sums -> cpart[rb][8192]; colsum cross-lane
// reduction deferred out of the loop (8 colp registers).
// Diagonal exp term (==1 for unit rows) kept; k_finish subtracts 1.
__global__ __launch_bounds__(256, 3) void k_simlse(
    const unsigned short* __restrict__ z,
    float* __restrict__ rpart,    // [16][8192]
    float* __restrict__ cpart,    // [128][8192]
    float* __restrict__ rowpos)   // [4096] (row r>=4096 mirrors r-4096)
{
  const int w = threadIdx.x >> 6;
  const int lane = threadIdx.x & 63;
  const int q = lane >> 4;
  const int c = lane & 15;

  // cell id -> (ch, rb): start(ch) = 4ch(ch+1), cells(ch) = 8(ch+1)
  int ch = 0;
  while ((int)blockIdx.x >= 4 * (ch + 1) * (ch + 2)) ++ch;
  const int rb = blockIdx.x - 4 * ch * (ch + 1);   // 0 .. 8ch+7
  const int R0 = rb << 6;                          // 64-row block
  const bool upper = (rb < (ch << 3));             // strictly above diagonal band

  // ---- A fragments straight from global: 16 contiguous 1KB loads ----
  bf16x8 a[4][4];
  {
    const unsigned short* ap = z + (R0 >> 4) * 2048 + (lane << 3);
    #pragma unroll
    for (int rg = 0; rg < 4; ++rg)
      #pragma unroll
      for (int kk = 0; kk < 4; ++kk)
        a[rg][kk] = *reinterpret_cast<const bf16x8*>(ap + rg * 2048 + kk * 512);
  }

  float acc[4][4];
  #pragma unroll
  for (int rg = 0; rg < 4; ++rg)
    #pragma unroll
    for (int e = 0; e < 4; ++e) acc[rg][e] = 0.0f;
  float pacc[4] = {0.f, 0.f, 0.f, 0.f};
  float colp[8];
  #pragma unroll
  for (int i = 0; i < 8; ++i) colp[i] = 0.0f;

  __shared__ float lsum[4][64];
  __shared__ float lpos[4][16];

  // wave w walks 16-col tiles ct = 32ch + w + 4i, i = 0..7
  const int ct0 = (ch << 5) + w;
  const unsigned short* bwave = z + ct0 * 2048 + (lane << 3);

  // positive tile: owned by this cell iff its 32-tile chunk matches.
  const int pos0t = ((R0 + 4096) & 8191) >> 4;
  const int ipb = ((pos0t >> 5) == ch) ? ((pos0t & 31) >> 2) : -99;

  bf16x8 b0[4], b1[4];
  auto ldb = [&](bf16x8 (&dst)[4], int idx) {
    const unsigned short* p = bwave + idx * 8192;   // stride 4 tiles
    dst[0] = *reinterpret_cast<const bf16x8*>(p);
    dst[1] = *reinterpret_cast<const bf16x8*>(p + 512);
    dst[2] = *reinterpret_cast<const bf16x8*>(p + 1024);
    dst[3] = *reinterpret_cast<const bf16x8*>(p + 1536);
  };

  auto process = [&](const bf16x8 (&bb)[4], int i) {
    f32x4 cc[4];
    #pragma unroll
    for (int rr = 0; rr < 4; ++rr) cc[rr] = f32x4{0.f, 0.f, 0.f, 0.f};
    #pragma unroll
    for (int kk = 0; kk < 4; ++kk)
      #pragma unroll
      for (int rr = 0; rr < 4; ++rr)
        cc[rr] = __builtin_amdgcn_mfma_f32_16x16x32_bf16(
            a[rr][kk], bb[kk], cc[rr], 0, 0, 0);
    float cp0 = 0.0f, cp1 = 0.0f;       // two chains to cut dep latency
    #pragma unroll
    for (int rr = 0; rr < 4; ++rr)
      #pragma unroll
      for (int e = 0; e < 4; ++e) {
        float tv = fast_exp2(__builtin_fmaf(cc[rr][e], EXP_SCALE, -EXP_SCALE));
        acc[rr][e] += tv;
        if (upper) { if (rr & 1) cp1 += tv; else cp0 += tv; }
      }
    if (upper) colp[i] = cp0 + cp1;     // NO shfl here — deferred
    if (i == ipb) {                     // rare, wave-uniform
      #pragma unroll
      for (int rr = 0; rr < 4; ++rr) {
        if (rr == w) {
          #pragma unroll
          for (int e = 0; e < 4; ++e)
            if (c == ((q << 2) + e)) pacc[e] = cc[rr][e] * 5.0f;
        }
      }
    }
  };

  ldb(b0, 0);
  #pragma unroll 1
  for (int i = 0; i < 8; i += 2) {
    ldb(b1, i + 1);
    process(b0, i);
    if (i + 2 < 8) ldb(b0, i + 2);
    process(b1, i + 1);
  }

  // Deferred colsum reduction: 8 independent values, shfls pipeline
  if (upper) {
    #pragma unroll
    for (int i = 0; i < 8; ++i) {
      float v = colp[i];
      v += __shfl_xor(v, 16, 64);
      v += __shfl_xor(v, 32, 64);
      if (lane < 16)
        cpart[(rb << 13) + (((ct0 + (i << 2)) << 4) + c)] = v;
    }
  }

  // Reduce row-sums over the 16 cols per tile (c-group: xor 1,2,4,8)
  #pragma unroll
  for (int m = 1; m < 16; m <<= 1) {
    #pragma unroll
    for (int rg = 0; rg < 4; ++rg)
      #pragma unroll
      for (int e = 0; e < 4; ++e)
        acc[rg][e] += __shfl_xor(acc[rg][e], m, 64);
    #pragma unroll
    for (int e = 0; e < 4; ++e) pacc[e] += __shfl_xor(pacc[e], m, 64);
  }

  if (c == 0) {
    #pragma unroll
    for (int rg = 0; rg < 4; ++rg)
      #pragma unroll
      for (int e = 0; e < 4; ++e)
        lsum[w][rg * 16 + (q << 2) + e] = acc[rg][e];
    #pragma unroll
    for (int e = 0; e < 4; ++e) lpos[w][(q << 2) + e] = pacc[e];
  }
  __syncthreads();

  if (threadIdx.x < 64) {
    const int t = threadIdx.x;
    float s = lsum[0][t] + lsum[1][t] + lsum[2][t] + lsum[3][t];
    rpart[(ch << 13) + R0 + t] = s;      // plain store, disjoint per cell
    if (ipb != -99)                      // this cell owns the positive cols
      rowpos[R0 + t] = lpos[t >> 4][t & 15];
  }
}

// Kernel 3: tot = sum of row-path partials (ch >= r>>9) + col-path partials
// (rb < 8*(r>>9)) - 1 (diagonal); lse = 5 + log(tot); loss = mean(lse - pos).
// pos for r>=4096 mirrors r-4096 (S symmetric).
__global__ __launch_bounds__(256) void k_finish(
    const float* __restrict__ rpart, const float* __restrict__ cpart,
    const float* __restrict__ rowpos, float* __restrict__ out)
{
  const int r = blockIdx.x * 256 + threadIdx.x;
  const int chr = r >> 9;                // uniform per block
  float t0 = -1.0f, t1 = 0.0f;
  for (int ch = chr; ch < 16; ++ch) t0 += rpart[(ch << 13) + r];
  const int nrb = chr << 3;
  #pragma unroll 4
  for (int rb = 0; rb < nrb; rb += 2) {  // nrb is even
    t0 += cpart[(rb << 13) + r];
    t1 += cpart[((rb + 1) << 13) + r];
  }
  float tot = t0 + t1;
  float v = 5.0f + logf(tot) - rowpos[r & 4095];
  #pragma unroll
  for (int m = 1; m < 64; m <<= 1) v += __shfl_xor(v, m, 64);
  __shared__ float red[4];
  if ((threadIdx.x & 63) == 0) red[threadIdx.x >> 6] = v;
  __syncthreads();
  if (threadIdx.x == 0)
    atomicAdd(out, (red[0] + red[1] + red[2] + red[3]) * (1.0f / 8192.0f));
}

extern "C" void kernel_launch(void* const* d_in, const int* in_sizes, int n_in,
                              void* d_out, int out_size, void* d_ws, size_t ws_size,
                              hipStream_t stream) {
  const float* emb_i = (const float*)d_in[0];
  const float* emb_j = (const float*)d_in[1];
  unsigned short* z = (unsigned short*)d_ws;                       // 2 MB (swizzled)
  float* rpart = (float*)((char*)d_ws + (2 << 20));                // [16][8192] = 512 KB
  float* cpart = rpart + 16 * 8192;                                // [128][8192] = 4 MB
  float* rowpos = cpart + 128 * 8192;                              // [4096] = 16 KB
  float* out = (float*)d_out;

  k_normalize<<<512, 256, 0, stream>>>(emb_i, emb_j, z, out);
  k_simlse<<<1088, 256, 0, stream>>>(z, rpart, cpart, rowpos);
  k_finish<<<32, 256, 0, stream>>>(rpart, cpart, rowpos, out);
}

// Round 10
// 75.958 us; speedup vs baseline: 1.0942x; 1.0915x over previous
//
#include <hip/hip_runtime.h>
#include <hip/hip_bf16.h>
#include <hip/hip_fp8.h>

typedef __attribute__((ext_vector_type(4))) float f32x4;
typedef long long i64;

// exp(v/T - 5) with T=0.2  ==  exp2( (v-1) * 5*log2(e) )
#define EXP_SCALE 7.213475204444817f

__device__ __forceinline__ float fast_exp2(float x) {
#if __has_builtin(__builtin_amdgcn_exp2f)
  return __builtin_amdgcn_exp2f(x);
#else
  return exp2f(x);
#endif
}

// z is stored as fp8 e4m3, SWIZZLED in MFMA-fragment order (byte units):
//   byte addr = tile*2048 + kk*512 + slot*8 + rem
// tile = row>>4, c = row&15; element e: kk = e>>5, q = (e>>3)&3, rem = e&7,
// slot = q*16 + c. A wave (lane = q*16+c) loads one (tile,kk) fragment as
// one contiguous 512B load (8B/lane dwordx2).

// Kernel 1: L2-normalize rows -> swizzled fp8 z. Block = one 16-row tile.
// Also zeroes rowsum (atomic target) and out[0].
__global__ __launch_bounds__(256) void k_normalize(
    const float* __restrict__ emb_i, const float* __restrict__ emb_j,
    unsigned char* __restrict__ z, float* __restrict__ rowsum,
    float* __restrict__ out)
{
  if (blockIdx.x == 0 && threadIdx.x == 0) out[0] = 0.0f;
  if (threadIdx.x < 16) rowsum[(blockIdx.x << 4) + threadIdx.x] = 0.0f;
  const int t = threadIdx.x;
  const int c = t >> 4;               // row within tile (0..15)
  const int sub = t & 15;             // 8-element block within row
  const int row = (blockIdx.x << 4) + c;
  const float* src = (row < 4096) ? (emb_i + row * 128) : (emb_j + (row - 4096) * 128);
  float4 v0 = reinterpret_cast<const float4*>(src)[sub * 2];
  float4 v1 = reinterpret_cast<const float4*>(src)[sub * 2 + 1];
  float ss = v0.x*v0.x + v0.y*v0.y + v0.z*v0.z + v0.w*v0.w
           + v1.x*v1.x + v1.y*v1.y + v1.z*v1.z + v1.w*v1.w;
  #pragma unroll
  for (int m = 1; m < 16; m <<= 1) ss += __shfl_xor(ss, m, 64);
  float rinv = 1.0f / sqrtf(ss);
  unsigned char st[8];
  st[0] = __hip_fp8_e4m3(v0.x * rinv).__x;
  st[1] = __hip_fp8_e4m3(v0.y * rinv).__x;
  st[2] = __hip_fp8_e4m3(v0.z * rinv).__x;
  st[3] = __hip_fp8_e4m3(v0.w * rinv).__x;
  st[4] = __hip_fp8_e4m3(v1.x * rinv).__x;
  st[5] = __hip_fp8_e4m3(v1.y * rinv).__x;
  st[6] = __hip_fp8_e4m3(v1.z * rinv).__x;
  st[7] = __hip_fp8_e4m3(v1.w * rinv).__x;
  // swizzled dst: kk = sub>>2, q = sub&3, slot = q*16 + c
  unsigned char* dst = z + blockIdx.x * 2048 + (sub >> 2) * 512 +
                       (((sub & 3) << 4) + c) * 8;
  *reinterpret_cast<i64*>(dst) = *reinterpret_cast<i64*>(st);
}

// Kernel 2 (symmetric, fp8 MFMA): cell = 64 rows x 512 cols, launched iff
// rb < 8(ch+1), ch 0..15 -> 1088 cells (53% of full work). A fragments
// straight from global (16 x 512B contiguous wave loads). Row-sums
// atomicAdd into rowsum; strictly-upper cells also atomicAdd column sums
// (transposed rows), cross-lane reduction deferred out of the loop.
// Diagonal exp term (==1 for unit rows) kept; k_finish subtracts 1.
__global__ __launch_bounds__(256, 4) void k_simlse(
    const unsigned char* __restrict__ z,
    float* __restrict__ rowsum,   // [8192], atomic accumulation
    float* __restrict__ rowpos)   // [4096] (row r>=4096 mirrors r-4096)
{
  const int w = threadIdx.x >> 6;
  const int lane = threadIdx.x & 63;
  const int q = lane >> 4;
  const int c = lane & 15;

  // cell id -> (ch, rb): start(ch) = 4ch(ch+1), cells(ch) = 8(ch+1)
  int ch = 0;
  while ((int)blockIdx.x >= 4 * (ch + 1) * (ch + 2)) ++ch;
  const int rb = blockIdx.x - 4 * ch * (ch + 1);   // 0 .. 8ch+7
  const int R0 = rb << 6;                          // 64-row block
  const bool upper = (rb < (ch << 3));             // strictly above diagonal band

  // ---- A fragments straight from global: 16 contiguous 512B loads ----
  i64 a[4][4];
  {
    const unsigned char* ap = z + (R0 >> 4) * 2048 + (lane << 3);
    #pragma unroll
    for (int rg = 0; rg < 4; ++rg)
      #pragma unroll
      for (int kk = 0; kk < 4; ++kk)
        a[rg][kk] = *reinterpret_cast<const i64*>(ap + rg * 2048 + kk * 512);
  }

  float acc[4][4];
  #pragma unroll
  for (int rg = 0; rg < 4; ++rg)
    #pragma unroll
    for (int e = 0; e < 4; ++e) acc[rg][e] = 0.0f;
  float pacc[4] = {0.f, 0.f, 0.f, 0.f};
  float colp[8];
  #pragma unroll
  for (int i = 0; i < 8; ++i) colp[i] = 0.0f;

  __shared__ float lsum[4][64];
  __shared__ float lpos[4][16];

  // wave w walks 16-col tiles ct = 32ch + w + 4i, i = 0..7
  const int ct0 = (ch << 5) + w;
  const unsigned char* bwave = z + ct0 * 2048 + (lane << 3);

  // positive tile: owned by this cell iff its 32-tile chunk matches.
  const int pos0t = ((R0 + 4096) & 8191) >> 4;
  const int ipb = ((pos0t >> 5) == ch) ? ((pos0t & 31) >> 2) : -99;

  i64 b0[4], b1[4];
  auto ldb = [&](i64 (&dst)[4], int idx) {
    const unsigned char* p = bwave + idx * 8192;   // stride 4 tiles = 8KB
    dst[0] = *reinterpret_cast<const i64*>(p);
    dst[1] = *reinterpret_cast<const i64*>(p + 512);
    dst[2] = *reinterpret_cast<const i64*>(p + 1024);
    dst[3] = *reinterpret_cast<const i64*>(p + 1536);
  };

  auto process = [&](const i64 (&bb)[4], int i) {
    f32x4 cc[4];
    #pragma unroll
    for (int rr = 0; rr < 4; ++rr) cc[rr] = f32x4{0.f, 0.f, 0.f, 0.f};
    #pragma unroll
    for (int kk = 0; kk < 4; ++kk)
      #pragma unroll
      for (int rr = 0; rr < 4; ++rr)
        cc[rr] = __builtin_amdgcn_mfma_f32_16x16x32_fp8_fp8(
            a[rr][kk], bb[kk], cc[rr], 0, 0, 0);
    float cp0 = 0.0f, cp1 = 0.0f;       // two chains to cut dep latency
    #pragma unroll
    for (int rr = 0; rr < 4; ++rr)
      #pragma unroll
      for (int e = 0; e < 4; ++e) {
        float tv = fast_exp2(__builtin_fmaf(cc[rr][e], EXP_SCALE, -EXP_SCALE));
        acc[rr][e] += tv;
        if (upper) { if (rr & 1) cp1 += tv; else cp0 += tv; }
      }
    if (upper) colp[i] = cp0 + cp1;     // shfl deferred out of the loop
    if (i == ipb) {                     // rare, wave-uniform
      #pragma unroll
      for (int rr = 0; rr < 4; ++rr) {
        if (rr == w) {
          #pragma unroll
          for (int e = 0; e < 4; ++e)
            if (c == ((q << 2) + e)) pacc[e] = cc[rr][e] * 5.0f;
        }
      }
    }
  };

  ldb(b0, 0);
  #pragma unroll 1
  for (int i = 0; i < 8; i += 2) {
    ldb(b1, i + 1);
    process(b0, i);
    if (i + 2 < 8) ldb(b0, i + 2);
    process(b1, i + 1);
  }

  // Deferred colsum reduction: 8 independent values, shfls pipeline
  if (upper) {
    #pragma unroll
    for (int i = 0; i < 8; ++i) {
      float v = colp[i];
      v += __shfl_xor(v, 16, 64);
      v += __shfl_xor(v, 32, 64);
      if (lane < 16)                    // col = (ct0+4i)*16 + c
        atomicAdd(&rowsum[((ct0 + (i << 2)) << 4) + c], v);
    }
  }

  // Reduce row-sums over the 16 cols per tile (c-group: xor 1,2,4,8)
  #pragma unroll
  for (int m = 1; m < 16; m <<= 1) {
    #pragma unroll
    for (int rg = 0; rg < 4; ++rg)
      #pragma unroll
      for (int e = 0; e < 4; ++e)
        acc[rg][e] += __shfl_xor(acc[rg][e], m, 64);
    #pragma unroll
    for (int e = 0; e < 4; ++e) pacc[e] += __shfl_xor(pacc[e], m, 64);
  }

  if (c == 0) {
    #pragma unroll
    for (int rg = 0; rg < 4; ++rg)
      #pragma unroll
      for (int e = 0; e < 4; ++e)
        lsum[w][rg * 16 + (q << 2) + e] = acc[rg][e];
    #pragma unroll
    for (int e = 0; e < 4; ++e) lpos[w][(q << 2) + e] = pacc[e];
  }
  __syncthreads();

  if (threadIdx.x < 64) {
    const int t = threadIdx.x;
    float s = lsum[0][t] + lsum[1][t] + lsum[2][t] + lsum[3][t];
    atomicAdd(&rowsum[R0 + t], s);
    if (ipb != -99)                     // this cell owns the positive cols
      rowpos[R0 + t] = lpos[t >> 4][t & 15];
  }
}

// Kernel 3: tot = rowsum - 1 (diagonal term); lse = 5 + log(tot);
// loss = mean(lse - pos). pos for r>=4096 mirrors r-4096 (S symmetric).
__global__ __launch_bounds__(256) void k_finish(
    const float* __restrict__ rowsum, const float* __restrict__ rowpos,
    float* __restrict__ out)
{
  const int r = blockIdx.x * 256 + threadIdx.x;
  float tot = rowsum[r] - 1.0f;
  float v = 5.0f + logf(tot) - rowpos[r & 4095];
  #pragma unroll
  for (int m = 1; m < 64; m <<= 1) v += __shfl_xor(v, m, 64);
  __shared__ float red[4];
  if ((threadIdx.x & 63) == 0) red[threadIdx.x >> 6] = v;
  __syncthreads();
  if (threadIdx.x == 0)
    atomicAdd(out, (red[0] + red[1] + red[2] + red[3]) * (1.0f / 8192.0f));
}

extern "C" void kernel_launch(void* const* d_in, const int* in_sizes, int n_in,
                              void* d_out, int out_size, void* d_ws, size_t ws_size,
                              hipStream_t stream) {
  const float* emb_i = (const float*)d_in[0];
  const float* emb_j = (const float*)d_in[1];
  unsigned char* z = (unsigned char*)d_ws;                         // 8192*128*1 = 1 MB (fp8, swizzled)
  float* rowsum = (float*)((char*)d_ws + (1 << 20));               // [8192] = 32 KB
  float* rowpos = rowsum + 8192;                                   // [4096] = 16 KB
  float* out = (float*)d_out;

  k_normalize<<<512, 256, 0, stream>>>(emb_i, emb_j, z, rowsum, out);
  k_simlse<<<1088, 256, 0, stream>>>(z, rowsum, rowpos);
  k_finish<<<32, 256, 0, stream>>>(rowsum, rowpos, out);
}